// Round 6
// baseline (312.510 us; speedup 1.0000x reference)
//
#include <hip/hip_runtime.h>
#include <math.h>

// ---------------- problem constants ----------------
#define SRATE   44100
#define T_IN    441000
#define BATCH   8
#define NB      3
#define NSEQ    (NB*BATCH)        // 24
#define TB_OUT  160000
#define NEW_R   160
#define ORIG_R  441
#define KW      475               // sinc kernel taps
#define KWP     476               // padded to /4
#define WIDTH   17
#define NFRAMES 1000

// IIR chunking: 441000 = 7875 * 56 ; warmup 128 (worst pole 0.9359 -> 2.1e-4 residual;
// proven at bf16 floor in R5). Smaller chunks = 189K threads = 2.9 waves/SIMD for latency hiding.
#define LCHUNK  56
#define NCHUNK  7875
#define WARM    128

// workspace layout
#define XLP_OFF (1u<<20)          // 1 MB; kt table at offset 0 (304,640 B)

// ---------------- sinc resample kernel table (replicates numpy f64 math) ----------------
__global__ void kt_init_kernel(float* __restrict__ kt) {
    int idx = blockIdx.x * blockDim.x + threadIdx.x;
    if (idx >= KWP * NEW_R) return;
    int j = idx / NEW_R, p = idx % NEW_R;   // layout kt[j][p] for coalesced phase-major reads
    float v = 0.f;
    if (j < KW) {
        const double base = 160.0 * 0.99;   // 158.4
        double t = (-(double)p) / 160.0 + ((double)(j - WIDTH)) / 441.0;
        t *= base;
        t = fmin(6.0, fmax(-6.0, t));
        double win = cos(t * M_PI / 6.0 / 2.0); win *= win;
        double tp = t * M_PI;
        double s = (tp == 0.0) ? 1.0 : sin(tp) / tp;
        v = (float)(s * win * (base / 441.0));
    }
    kt[idx] = v;
}

// ---------------- fused bandpass -> clip -> cos mix -> lowpass -> clip scan (all f32) ----
// Heterodyne replicates the XLA-f32 reference arithmetic (validated R5, absmax = bf16 floor):
//   tf = fl32( fl32(n) * fl32(1/44100) ), X = fl32( w_f32 * tf )
// cos(X) via 2-term f32 Cody-Waite reduction (exact fma chain, phase err ~5e-7 rad) + v_cos_f32.
struct ScanParams {
    float b0[NB], a1[NB], a2[NB], w[NB];
    float lb0, lb1, lb2, la1, la2;
};

__global__ __launch_bounds__(256) void scan_kernel(const float* __restrict__ x,
                                                   float* __restrict__ xlp,
                                                   ScanParams P) {
    int id = blockIdx.x * blockDim.x + threadIdx.x;
    if (id >= NSEQ * NCHUNK) return;
    int seq   = id / NCHUNK;          // consecutive lanes = consecutive chunks of one seq
    int chunk = id - seq * NCHUNK;
    int band  = seq / BATCH;
    int batch = seq - band * BATCH;

    float b0f = (band == 0) ? P.b0[0] : (band == 1) ? P.b0[1] : P.b0[2];
    float a1f = (band == 0) ? P.a1[0] : (band == 1) ? P.a1[1] : P.a1[2];
    float a2f = (band == 0) ? P.a2[0] : (band == 1) ? P.a2[1] : P.a2[2];
    float wf  = (band == 0) ? P.w[0]  : (band == 1) ? P.w[1]  : P.w[2];
    float b2f = -b0f;                 // bandpass b2 = -b0
    float lb0 = P.lb0, lb1 = P.lb1, lb2 = P.lb2, la1 = P.la1, la2 = P.la2;

    const float*  xr   = x + batch * T_IN;
    float*        orow = xlp + seq * T_IN;
    const float4* xr4  = (const float4*)xr;

    int t0 = chunk * LCHUNK;          // multiple of 4 -> float4 aligned
    int s0 = t0 - WARM; if (s0 < 0) s0 = 0;
    int e  = t0 + LCHUNK;

    float bx1 = 0.f, bx2 = 0.f, by1 = 0.f, by2 = 0.f;   // bandpass state (UNclipped feedback)
    float mx1 = 0.f, mx2 = 0.f, mz1 = 0.f, mz2 = 0.f;   // lowpass state

    const float invsr   = 1.0f / 44100.0f;       // fl32(1/44100) -- XLA's folded reciprocal
    const float INV2PI  = 0.15915494309189535f;  // fl32(1/2pi)
    const float PI2_A   = 6.28318548202514648f;  // fl32(2pi)
    const float PI2_B   = -1.7484556000744487e-7f; // fl32(2pi - (double)PI2_A)

    float4 xv = xr4[s0 >> 2];
    for (int s = s0; s < e; s += 4) {
        float4 xn;
        if (s + 4 < e) xn = xr4[(s >> 2) + 1];
        else           xn = make_float4(0.f, 0.f, 0.f, 0.f);

        float o0, o1, o2, o3;
#define STEP(XT, TI, OUT) {                                                   \
        float y  = b0f*(XT) + b2f*bx2 - a1f*by1 - a2f*by2;                    \
        bx2 = bx1; bx1 = (XT); by2 = by1; by1 = y;                            \
        float cy = fminf(fmaxf(y, -1.f), 1.f);                                \
        float tf = (float)(TI) * invsr;      /* == XLA reciprocal-mul */      \
        float X  = wf * tf;                  /* == XLA f32 product    */      \
        float kk = __builtin_rintf(X * INV2PI);                               \
        float r  = fmaf(-kk, PI2_A, X);                                       \
        r        = fmaf(-kk, PI2_B, r);      /* r = X mod 2pi, exact */       \
        float cv = __builtin_amdgcn_cosf(r * INV2PI);  /* rev input */        \
        float m  = cy * cv;                                                   \
        float z  = lb0*m + lb1*mx1 + lb2*mx2 - la1*mz1 - la2*mz2;             \
        mx2 = mx1; mx1 = m; mz2 = mz1; mz1 = z;                               \
        OUT = fminf(fmaxf(z, -1.f), 1.f); }

        STEP(xv.x, s,     o0)
        STEP(xv.y, s + 1, o1)
        STEP(xv.z, s + 2, o2)
        STEP(xv.w, s + 3, o3)
#undef STEP
        if (s >= t0) ((float4*)orow)[s >> 2] = make_float4(o0, o1, o2, o3);
        xv = xn;
    }
}

// ---------------- polyphase resample: out[seq,f,p] = sum_j kt[j][p] * xlp[f*441 + j - 17] ----------------
// FB=16 frames/block, ROWW=484: row bank-offset = (f*484)%32 = f*4 -> the 8 fg-rows per wave
// hit 8 distinct bank quads -> conflict-free ds_read_b128. LDS 31 KB -> 5 blocks/CU.
#define FB    16
#define ROWW  484     // 484*4 B = 1936 = 121*16 -> rows stay 16-B aligned

__device__ inline void fma4(float4& a, float s, const float4& k) {
    a.x += s * k.x; a.y += s * k.y; a.z += s * k.z; a.w += s * k.w;
}

#define FGB   63      // frame-groups (blocks) per sequence: 63*16 = 1008 >= 1000

__global__ __launch_bounds__(160) void resample_kernel(const float* __restrict__ xlp,
                                                       const float* __restrict__ kt,
                                                       float* __restrict__ out) {
    __shared__ float xs[FB * ROWW];   // 30,976 B
    int bid = blockIdx.x;
    int seq = bid / FGB;
    int bg  = bid - seq * FGB;
    int f0  = bg * FB;
    int band  = seq / BATCH;
    int batch = seq - band * BATCH;
    const float* xr = xlp + seq * T_IN;

    // stage x windows: row f holds xlp[(f0+f)*441 - 17 .. +458], OOB/pad -> 0
    for (int i = threadIdx.x; i < FB * ROWW; i += 160) {
        int f = i / ROWW, c = i - f * ROWW;
        float v = 0.f;
        int src = (f0 + f) * ORIG_R - WIDTH + c;
        if (c < KWP && src >= 0 && src < T_IN) v = xr[src];
        xs[i] = v;
    }
    __syncthreads();

    int pg = threadIdx.x % 20;        // 20 phase-groups x 8 phases = 160
    int fg = threadIdx.x / 20;        // 8 fg, frames {fg, fg+8}
    int p0 = pg * 8;

    float4 acc[2][2];
#pragma unroll
    for (int f = 0; f < 2; ++f) {
        acc[f][0] = make_float4(0.f, 0.f, 0.f, 0.f);
        acc[f][1] = make_float4(0.f, 0.f, 0.f, 0.f);
    }

    const float* xrow0 = &xs[fg * ROWW];
    const float* xrow1 = &xs[(fg + 8) * ROWW];

    for (int jt = 0; jt < KWP / 4; ++jt) {   // 119 tiles of 4 taps
        int j = jt << 2;
        const float* kr = kt + j * NEW_R + p0;
        float4 k0a = *(const float4*)(kr);
        float4 k0b = *(const float4*)(kr + 4);
        float4 k1a = *(const float4*)(kr + NEW_R);
        float4 k1b = *(const float4*)(kr + NEW_R + 4);
        float4 k2a = *(const float4*)(kr + 2 * NEW_R);
        float4 k2b = *(const float4*)(kr + 2 * NEW_R + 4);
        float4 k3a = *(const float4*)(kr + 3 * NEW_R);
        float4 k3b = *(const float4*)(kr + 3 * NEW_R + 4);

        float4 xv0 = *(const float4*)(xrow0 + j);   // aligned b128, conflict-free
        float4 xv1 = *(const float4*)(xrow1 + j);

        fma4(acc[0][0], xv0.x, k0a); fma4(acc[0][1], xv0.x, k0b);
        fma4(acc[0][0], xv0.y, k1a); fma4(acc[0][1], xv0.y, k1b);
        fma4(acc[0][0], xv0.z, k2a); fma4(acc[0][1], xv0.z, k2b);
        fma4(acc[0][0], xv0.w, k3a); fma4(acc[0][1], xv0.w, k3b);

        fma4(acc[1][0], xv1.x, k0a); fma4(acc[1][1], xv1.x, k0b);
        fma4(acc[1][0], xv1.y, k1a); fma4(acc[1][1], xv1.y, k1b);
        fma4(acc[1][0], xv1.z, k2a); fma4(acc[1][1], xv1.z, k2b);
        fma4(acc[1][0], xv1.w, k3a); fma4(acc[1][1], xv1.w, k3b);
    }

    int obase = (batch * NB + band) * TB_OUT;   // output is (B, nb, Tb)
#pragma unroll
    for (int f = 0; f < 2; ++f) {
        int fr = f0 + fg + f * 8;
        if (fr < NFRAMES) {
            float4* o = (float4*)(out + obase + fr * NEW_R + p0);
            o[0] = acc[f][0];
            o[1] = acc[f][1];
        }
    }
}

// ---------------- host ----------------
extern "C" void kernel_launch(void* const* d_in, const int* in_sizes, int n_in,
                              void* d_out, int out_size, void* d_ws, size_t ws_size,
                              hipStream_t stream) {
    const float* x   = (const float*)d_in[0];
    float*       out = (float*)d_out;
    float*       kt  = (float*)d_ws;
    float*       xlp = (float*)((char*)d_ws + XLP_OFF);

    // biquad coefficients computed in f64 on host, cast f32 (bit-matches reference)
    ScanParams P;
    const double centers[NB] = {4000.0, 12000.0, 19025.0};
    const double Qs[NB]      = {0.5, 1.5, 19025.0 / 6050.0};
    for (int b = 0; b < NB; ++b) {
        double c  = centers[b], Q = Qs[b];
        double w0 = 2.0 * M_PI * c / 44100.0;
        double al = sin(w0) / (2.0 * Q);
        double a0 = 1.0 + al;
        P.b0[b] = (float)(al / a0);
        P.a1[b] = (float)(-2.0 * cos(w0) / a0);
        P.a2[b] = (float)((1.0 - al) / a0);
        // w = fl32(fl32(2pi) * fl32(c)) -- f32 weak-scalar product, as jax/np compute it
        P.w[b]  = 6.283185307179586f * (float)c;
    }
    {
        double cut = 0.45 * 16000.0;                 // 7200
        double Q   = 0.7071067811865476;
        double w0  = 2.0 * M_PI * cut / 44100.0;
        double al  = sin(w0) / (2.0 * Q);
        double cs  = cos(w0);
        double a0  = 1.0 + al;
        P.lb0 = (float)(((1.0 - cs) / 2.0) / a0);
        P.lb1 = (float)((1.0 - cs) / a0);
        P.lb2 = P.lb0;
        P.la1 = (float)(-2.0 * cs / a0);
        P.la2 = (float)((1.0 - al) / a0);
    }

    // 1) sinc table (476x160 f32, ~305 KB at ws+0)
    kt_init_kernel<<<dim3((KWP * NEW_R + 255) / 256), dim3(256), 0, stream>>>(kt);

    // 2) fused IIR cascade -> xlp (24 x 441000 f32 at ws+1MB), 189000 warm-up chunks
    int nthreads = NSEQ * NCHUNK;                    // 189000
    scan_kernel<<<dim3((nthreads + 255) / 256), dim3(256), 0, stream>>>(x, xlp, P);

    // 3) polyphase resample -> out (8 x 3 x 160000)
    resample_kernel<<<dim3(NSEQ * FGB), dim3(160), 0, stream>>>(xlp, kt, out);
}

// Round 7
// 152.868 us; speedup vs baseline: 2.0443x; 2.0443x over previous
//
#include <hip/hip_runtime.h>
#include <math.h>

// ---------------- problem constants ----------------
#define SRATE   44100
#define T_IN    441000
#define BATCH   8
#define NB      3
#define NSEQ    (NB*BATCH)        // 24
#define TB_OUT  160000
#define NEW_R   160
#define ORIG_R  441
#define KW      475               // sinc taps
#define KP      480               // K padded to 15*32 for MFMA
#define WIDTH   17
#define NFRAMES 1000

// IIR chunking: 441000 = 2625 * 168 ; warmup 128 (validated R5/R6 at bf16 floor)
#define LCHUNK  168
#define NCHUNK  2625
#define WARM    128

// workspace layout
#define KTH_OFF 0                 // 160*480 ushort = 153.6 KB
#define KTL_OFF (256u<<10)        // 256 KB
#define XLP_OFF (1u<<20)          // 1 MB; xlp = 24*441000 f32 = 42.3 MB

typedef __attribute__((ext_vector_type(4))) float floatx4;
typedef __attribute__((ext_vector_type(8))) short short8;

// bf16 helpers (RNE)
__device__ inline unsigned short f2bf(float f) {
    union { float f; unsigned u; } v; v.f = f;
    unsigned u = v.u, r = (u >> 16) & 0xffffu, rem = u & 0xffffu;
    if (rem > 0x8000u || (rem == 0x8000u && (r & 1u))) r++;
    return (unsigned short)r;
}
__device__ inline float bf2f(unsigned short h) {
    union { unsigned u; float f; } v; v.u = ((unsigned)h) << 16; return v.f;
}

// ---------------- sinc table -> transposed bf16-split: ktT[p][k], k=tap ----------------
// f64 only for cheap mul/add + exact range reduction; transcendentals are f32 v_sin/v_cos.
__global__ void kt_init_kernel(unsigned short* __restrict__ kth,
                               unsigned short* __restrict__ ktl) {
    int idx = blockIdx.x * blockDim.x + threadIdx.x;
    if (idx >= NEW_R * KP) return;
    int p = idx / KP, k = idx - p * KP;
    float v = 0.f;
    if (k < KW) {
        double t = (double)(k - WIDTH) * (158.4 / 441.0) - (double)p * 0.99;
        t = fmin(6.0, fmax(-6.0, t));
        // window: cos(pi*t/12)^2 -> cos_rev(t/24), |t/24| <= 0.25
        float wc = __builtin_amdgcn_cosf((float)(t * (1.0 / 24.0)));
        // sin(pi*t): n=rint(t), r=t-n in [-0.5,0.5]; sin(pi t) = (-1)^n sin(pi r)
        double n = rint(t);
        float r2 = (float)((t - n) * 0.5);            // revolutions, |.|<=0.25
        float sp = __builtin_amdgcn_sinf(r2 - floorf(r2));
        if (((long long)n) & 1) sp = -sp;
        float tp = (float)(t * M_PI);
        float snc = (t == 0.0) ? 1.f : sp / tp;
        v = snc * wc * wc * 0.3591836734693878f;      // * base/441
    }
    unsigned short h = f2bf(v);
    kth[idx] = h;
    ktl[idx] = f2bf(v - bf2f(h));
}

// ---------------- fused bandpass -> clip -> cos mix -> lowpass -> clip scan (all f32) ----
// Heterodyne = XLA-f32 arithmetic (validated R5/R6 at bf16 floor):
//   tf = fl32(n)*fl32(1/44100); X = fl32(w_f32*tf); cos via f32 Cody-Waite + v_cos.
struct ScanParams {
    float b0[NB], a1[NB], a2[NB], w[NB];
    float lb0, lb1, lb2, la1, la2;
};

__global__ __launch_bounds__(256) void scan_kernel(const float* __restrict__ x,
                                                   float* __restrict__ xlp,
                                                   ScanParams P) {
    int id = blockIdx.x * blockDim.x + threadIdx.x;
    if (id >= NSEQ * NCHUNK) return;
    int seq   = id / NCHUNK;
    int chunk = id - seq * NCHUNK;
    int band  = seq / BATCH;
    int batch = seq - band * BATCH;

    float b0f = (band == 0) ? P.b0[0] : (band == 1) ? P.b0[1] : P.b0[2];
    float a1f = (band == 0) ? P.a1[0] : (band == 1) ? P.a1[1] : P.a1[2];
    float a2f = (band == 0) ? P.a2[0] : (band == 1) ? P.a2[1] : P.a2[2];
    float wf  = (band == 0) ? P.w[0]  : (band == 1) ? P.w[1]  : P.w[2];
    float b2f = -b0f;
    float lb0 = P.lb0, lb1 = P.lb1, lb2 = P.lb2, la1 = P.la1, la2 = P.la2;

    const float*  xr   = x + batch * T_IN;
    float*        orow = xlp + seq * T_IN;
    const float4* xr4  = (const float4*)xr;

    int t0 = chunk * LCHUNK;
    int s0 = t0 - WARM; if (s0 < 0) s0 = 0;
    int e  = t0 + LCHUNK;

    float bx1 = 0.f, bx2 = 0.f, by1 = 0.f, by2 = 0.f;
    float mx1 = 0.f, mx2 = 0.f, mz1 = 0.f, mz2 = 0.f;

    const float invsr  = 1.0f / 44100.0f;
    const float INV2PI = 0.15915494309189535f;
    const float PI2_A  = 6.28318548202514648f;
    const float PI2_B  = -1.7484556000744487e-7f;

    int nv = (e - s0) >> 2;
    const float4* pp = xr4 + (s0 >> 2);
    float4 f0v = pp[0];
    float4 f1v = (1 < nv) ? pp[1] : make_float4(0.f, 0.f, 0.f, 0.f);

    for (int i = 0; i < nv; ++i) {
        float4 cur = f0v;
        f0v = f1v;
        f1v = (i + 2 < nv) ? pp[i + 2] : make_float4(0.f, 0.f, 0.f, 0.f);
        int s = s0 + (i << 2);

        float o0, o1, o2, o3;
#define STEP(XT, TI, OUT) {                                                   \
        float y  = b0f*(XT) + b2f*bx2 - a1f*by1 - a2f*by2;                    \
        bx2 = bx1; bx1 = (XT); by2 = by1; by1 = y;                            \
        float cy = fminf(fmaxf(y, -1.f), 1.f);                                \
        float tf = (float)(TI) * invsr;                                       \
        float X  = wf * tf;                                                   \
        float kk = __builtin_rintf(X * INV2PI);                               \
        float r  = fmaf(-kk, PI2_A, X);                                       \
        r        = fmaf(-kk, PI2_B, r);                                       \
        float cv = __builtin_amdgcn_cosf(r * INV2PI);                         \
        float m  = cy * cv;                                                   \
        float z  = lb0*m + lb1*mx1 + lb2*mx2 - la1*mz1 - la2*mz2;             \
        mx2 = mx1; mx1 = m; mz2 = mz1; mz1 = z;                               \
        OUT = fminf(fmaxf(z, -1.f), 1.f); }

        STEP(cur.x, s,     o0)
        STEP(cur.y, s + 1, o1)
        STEP(cur.z, s + 2, o2)
        STEP(cur.w, s + 3, o3)
#undef STEP
        if (s >= t0) ((float4*)orow)[s >> 2] = make_float4(o0, o1, o2, o3);
    }
}

// ---------------- MFMA resample: out[f,p] = sum_k x[f*441+k-17] * kt[k][p] ----------------
// Split-bf16 GEMM: 3 passes (xh*kh + xh*kl + xl*kh), f32 accumulate. 16-frame M-tiles,
// 5 waves x 32 phases = 160 phases/block. A from LDS (488-pad: 976B row = 61 b128-slots,
// gcd(61,8)=1 -> 2 lanes/slot = conflict-free). B straight from global (L2-resident 307 KB).
#define MT    63      // M-tiles per sequence: 63*16 = 1008 >= 1000
#define XROW  488

__global__ __launch_bounds__(320) void resample_mfma(const float* __restrict__ xlp,
                                                     const unsigned short* __restrict__ kth,
                                                     const unsigned short* __restrict__ ktl,
                                                     float* __restrict__ out) {
    __shared__ unsigned short xh[16 * XROW];
    __shared__ unsigned short xl[16 * XROW];
    int bid = blockIdx.x;
    int seq = bid / MT;
    int mt  = bid - seq * MT;
    int band  = seq / BATCH;
    int batch = seq - band * BATCH;
    int f0 = mt * 16;
    const float* xr = xlp + seq * T_IN;

    // stage 16 frame-windows, split to bf16 hi/lo
    for (int i = threadIdx.x; i < 16 * KP; i += 320) {
        int r = i / KP, c = i - r * KP;
        float v = 0.f;
        int src = (f0 + r) * ORIG_R - WIDTH + c;
        if (c < KW && src >= 0 && src < T_IN) v = xr[src];
        unsigned short h = f2bf(v);
        xh[r * XROW + c] = h;
        xl[r * XROW + c] = f2bf(v - bf2f(h));
    }
    __syncthreads();

    int wave = threadIdx.x >> 6;
    int lane = threadIdx.x & 63;
    int l15  = lane & 15;
    int quad = lane >> 4;
    int p0   = wave * 32;

    floatx4 acc0 = {0.f, 0.f, 0.f, 0.f};
    floatx4 acc1 = {0.f, 0.f, 0.f, 0.f};

    const unsigned short* arow_h = &xh[l15 * XROW + quad * 8];   // A[m=l15][k]
    const unsigned short* arow_l = &xl[l15 * XROW + quad * 8];
    const unsigned short* b0h = kth + (p0 + l15) * KP + quad * 8;      // B[k][n=l15]
    const unsigned short* b0l = ktl + (p0 + l15) * KP + quad * 8;
    const unsigned short* b1h = kth + (p0 + 16 + l15) * KP + quad * 8;
    const unsigned short* b1l = ktl + (p0 + 16 + l15) * KP + quad * 8;

#pragma unroll
    for (int ks = 0; ks < KP / 32; ++ks) {       // 15 K-steps of 32
        int k0 = ks * 32;
        short8 ah = *(const short8*)(arow_h + k0);
        short8 al = *(const short8*)(arow_l + k0);
        short8 kh0 = *(const short8*)(b0h + k0);
        short8 kl0 = *(const short8*)(b0l + k0);
        short8 kh1 = *(const short8*)(b1h + k0);
        short8 kl1 = *(const short8*)(b1l + k0);
        acc0 = __builtin_amdgcn_mfma_f32_16x16x32_bf16(ah, kh0, acc0, 0, 0, 0);
        acc0 = __builtin_amdgcn_mfma_f32_16x16x32_bf16(ah, kl0, acc0, 0, 0, 0);
        acc0 = __builtin_amdgcn_mfma_f32_16x16x32_bf16(al, kh0, acc0, 0, 0, 0);
        acc1 = __builtin_amdgcn_mfma_f32_16x16x32_bf16(ah, kh1, acc1, 0, 0, 0);
        acc1 = __builtin_amdgcn_mfma_f32_16x16x32_bf16(ah, kl1, acc1, 0, 0, 0);
        acc1 = __builtin_amdgcn_mfma_f32_16x16x32_bf16(al, kh1, acc1, 0, 0, 0);
    }

    // C/D layout: n = lane&15, m = quad*4 + reg (m89/m91-verified)
    int obase = (batch * NB + band) * TB_OUT;
#pragma unroll
    for (int r = 0; r < 4; ++r) {
        int fr = f0 + quad * 4 + r;
        if (fr < NFRAMES) {
            out[obase + fr * NEW_R + p0 + l15]      = acc0[r];
            out[obase + fr * NEW_R + p0 + 16 + l15] = acc1[r];
        }
    }
}

// ---------------- host ----------------
extern "C" void kernel_launch(void* const* d_in, const int* in_sizes, int n_in,
                              void* d_out, int out_size, void* d_ws, size_t ws_size,
                              hipStream_t stream) {
    const float*    x   = (const float*)d_in[0];
    float*          out = (float*)d_out;
    unsigned short* kth = (unsigned short*)((char*)d_ws + KTH_OFF);
    unsigned short* ktl = (unsigned short*)((char*)d_ws + KTL_OFF);
    float*          xlp = (float*)((char*)d_ws + XLP_OFF);

    ScanParams P;
    const double centers[NB] = {4000.0, 12000.0, 19025.0};
    const double Qs[NB]      = {0.5, 1.5, 19025.0 / 6050.0};
    for (int b = 0; b < NB; ++b) {
        double c  = centers[b], Q = Qs[b];
        double w0 = 2.0 * M_PI * c / 44100.0;
        double al = sin(w0) / (2.0 * Q);
        double a0 = 1.0 + al;
        P.b0[b] = (float)(al / a0);
        P.a1[b] = (float)(-2.0 * cos(w0) / a0);
        P.a2[b] = (float)((1.0 - al) / a0);
        P.w[b]  = 6.283185307179586f * (float)c;   // fl32(fl32(2pi)*c), validated
    }
    {
        double cut = 0.45 * 16000.0;
        double Q   = 0.7071067811865476;
        double w0  = 2.0 * M_PI * cut / 44100.0;
        double al  = sin(w0) / (2.0 * Q);
        double cs  = cos(w0);
        double a0  = 1.0 + al;
        P.lb0 = (float)(((1.0 - cs) / 2.0) / a0);
        P.lb1 = (float)((1.0 - cs) / a0);
        P.lb2 = P.lb0;
        P.la1 = (float)(-2.0 * cs / a0);
        P.la2 = (float)((1.0 - al) / a0);
    }

    // 1) bf16-split transposed sinc tables (160x480 each)
    kt_init_kernel<<<dim3((NEW_R * KP + 255) / 256), dim3(256), 0, stream>>>(kth, ktl);

    // 2) fused IIR cascade -> xlp (24 x 441000 f32)
    int nthreads = NSEQ * NCHUNK;                    // 63000
    scan_kernel<<<dim3((nthreads + 255) / 256), dim3(256), 0, stream>>>(x, xlp, P);

    // 3) MFMA polyphase resample -> out (8 x 3 x 160000)
    resample_mfma<<<dim3(NSEQ * MT), dim3(320), 0, stream>>>(xlp, kth, ktl, out);
}

// Round 8
// 137.060 us; speedup vs baseline: 2.2801x; 1.1153x over previous
//
#include <hip/hip_runtime.h>
#include <math.h>

// ---------------- problem constants ----------------
#define SRATE   44100
#define T_IN    441000
#define BATCH   8
#define NB      3
#define NSEQ    (NB*BATCH)        // 24
#define TB_OUT  160000
#define NEW_R   160
#define ORIG_R  441
#define KW      475               // sinc taps
#define KP      480               // K padded to 15*32 for MFMA
#define WIDTH   17
#define NFRAMES 1000

// IIR chunking: 441000 = 2625 * 168 ; warmup 120 (pole 0.9357 -> e^-7.97 = 3.4e-4 residual,
// R5 proved 2.1e-4 is at the bf16 comparison floor; span 288 = 18 exact 16-sample groups)
#define LCHUNK  168
#define NCHUNK  2625
#define WARM    120

// workspace layout
#define KTH_OFF 0                 // frag-major bf16-hi table: 160*480 ushort = 153.6 KB
#define KTL_OFF (256u<<10)        // bf16-lo table
#define XLP_OFF (1u<<20)          // xlp f32: 24*441000*4 = 42.3 MB

typedef __attribute__((ext_vector_type(4))) float floatx4;
typedef __attribute__((ext_vector_type(8))) short short8;

// bf16 helpers (RNE) — proven R7
__device__ inline unsigned short f2bf(float f) {
    union { float f; unsigned u; } v; v.f = f;
    unsigned u = v.u, r = (u >> 16) & 0xffffu, rem = u & 0xffffu;
    if (rem > 0x8000u || (rem == 0x8000u && (r & 1u))) r++;
    return (unsigned short)r;
}
__device__ inline float bf2f(unsigned short h) {
    union { unsigned u; float f; } v; v.u = ((unsigned)h) << 16; return v.f;
}

// frag-major flat index: element ktT[p][k] with p = pblk*16+n, k = ks*32 + qd*8 + j
// -> flat = pblk*7680 + ks*512 + (qd*16+n)*8 + j  (wave load = contiguous 1KB)
__device__ inline int fragB(int p, int k) {
    int pblk = p >> 4, n = p & 15;
    int ks = k >> 5, qd = (k >> 3) & 3, j = k & 7;
    return pblk * 7680 + ks * 512 + (qd * 16 + n) * 8 + j;
}

// ---------------- sinc table -> frag-major bf16-split (math proven R7) ----------------
__global__ void kt_init_kernel(unsigned short* __restrict__ kth,
                               unsigned short* __restrict__ ktl) {
    int idx = blockIdx.x * blockDim.x + threadIdx.x;
    if (idx >= NEW_R * KP) return;
    int p = idx / KP, k = idx - p * KP;
    float v = 0.f;
    if (k < KW) {
        double t = (double)(k - WIDTH) * (158.4 / 441.0) - (double)p * 0.99;
        t = fmin(6.0, fmax(-6.0, t));
        float wc = __builtin_amdgcn_cosf((float)(t * (1.0 / 24.0)));
        double n = rint(t);
        float r2 = (float)((t - n) * 0.5);
        float sp = __builtin_amdgcn_sinf(r2 - floorf(r2));
        if (((long long)n) & 1) sp = -sp;
        float tp = (float)(t * M_PI);
        float snc = (t == 0.0) ? 1.f : sp / tp;
        v = snc * wc * wc * 0.3591836734693878f;
    }
    unsigned short h = f2bf(v);
    int flat = fragB(p, k);
    kth[flat] = h;
    ktl[flat] = f2bf(v - bf2f(h));
}

// ---------------- fused bandpass -> clip -> cos mix -> lowpass -> clip scan (f32) ----
// Heterodyne = XLA-f32 arithmetic (validated R5-R7 at bf16 floor).
// 4-deep float4 prefetch ring: 16-sample lookahead covers ~900-cyc HBM latency.
struct ScanParams {
    float b0[NB], a1[NB], a2[NB], w[NB];
    float lb0, lb1, lb2, la1, la2;
};

__global__ __launch_bounds__(256) void scan_kernel(const float* __restrict__ x,
                                                   float* __restrict__ xlp,
                                                   ScanParams P) {
    int id = blockIdx.x * blockDim.x + threadIdx.x;
    if (id >= NSEQ * NCHUNK) return;
    int seq   = id / NCHUNK;
    int chunk = id - seq * NCHUNK;
    int band  = seq / BATCH;
    int batch = seq - band * BATCH;

    float b0f = (band == 0) ? P.b0[0] : (band == 1) ? P.b0[1] : P.b0[2];
    float a1f = (band == 0) ? P.a1[0] : (band == 1) ? P.a1[1] : P.a1[2];
    float a2f = (band == 0) ? P.a2[0] : (band == 1) ? P.a2[1] : P.a2[2];
    float wf  = (band == 0) ? P.w[0]  : (band == 1) ? P.w[1]  : P.w[2];
    float b2f = -b0f;
    float lb0 = P.lb0, lb1 = P.lb1, lb2 = P.lb2, la1 = P.la1, la2 = P.la2;

    const float*  xr   = x + batch * T_IN;
    float*        orow = xlp + seq * T_IN;
    const float4* xr4  = (const float4*)xr;

    int t0 = chunk * LCHUNK;
    int s0 = t0 - WARM; if (s0 < 0) s0 = 0;
    int e  = t0 + LCHUNK;
    int nq = (e - s0) >> 2;           // 72 (chunk 0: 42)

    float bx1 = 0.f, bx2 = 0.f, by1 = 0.f, by2 = 0.f;
    float mx1 = 0.f, mx2 = 0.f, mz1 = 0.f, mz2 = 0.f;

    const float invsr  = 1.0f / 44100.0f;
    const float INV2PI = 0.15915494309189535f;
    const float PI2_A  = 6.28318548202514648f;
    const float PI2_B  = -1.7484556000744487e-7f;

    const float4 zero = make_float4(0.f, 0.f, 0.f, 0.f);
    const float4* pp = xr4 + (s0 >> 2);
    float4 c0 = pp[0];
    float4 c1 = (1 < nq) ? pp[1] : zero;
    float4 c2 = (2 < nq) ? pp[2] : zero;
    float4 c3 = (3 < nq) ? pp[3] : zero;

    for (int iq = 0; iq < nq; iq += 4) {
        float4 n0 = (iq + 4 < nq) ? pp[iq + 4] : zero;
        float4 n1 = (iq + 5 < nq) ? pp[iq + 5] : zero;
        float4 n2 = (iq + 6 < nq) ? pp[iq + 6] : zero;
        float4 n3 = (iq + 7 < nq) ? pp[iq + 7] : zero;

#define STEP(XT, TI, OUT) {                                                   \
        float y  = b0f*(XT) + b2f*bx2 - a1f*by1 - a2f*by2;                    \
        bx2 = bx1; bx1 = (XT); by2 = by1; by1 = y;                            \
        float cy = fminf(fmaxf(y, -1.f), 1.f);                                \
        float tf = (float)(TI) * invsr;                                       \
        float X  = wf * tf;                                                   \
        float kk = __builtin_rintf(X * INV2PI);                               \
        float r  = fmaf(-kk, PI2_A, X);                                       \
        r        = fmaf(-kk, PI2_B, r);                                       \
        float cv = __builtin_amdgcn_cosf(r * INV2PI);                         \
        float m  = cy * cv;                                                   \
        float z  = lb0*m + lb1*mx1 + lb2*mx2 - la1*mz1 - la2*mz2;             \
        mx2 = mx1; mx1 = m; mz2 = mz1; mz1 = z;                               \
        OUT = fminf(fmaxf(z, -1.f), 1.f); }

#define QUAD(CV, QI) {                                                        \
        int s = s0 + ((iq + QI) << 2);                                        \
        float o0, o1, o2, o3;                                                 \
        STEP(CV.x, s,     o0)                                                 \
        STEP(CV.y, s + 1, o1)                                                 \
        STEP(CV.z, s + 2, o2)                                                 \
        STEP(CV.w, s + 3, o3)                                                 \
        if (s >= t0 && s < e)                                                 \
            ((float4*)orow)[s >> 2] = make_float4(o0, o1, o2, o3); }

        QUAD(c0, 0)
        QUAD(c1, 1)
        QUAD(c2, 2)
        QUAD(c3, 3)
#undef QUAD
#undef STEP
        c0 = n0; c1 = n1; c2 = n2; c3 = n3;
    }
}

// ---------------- MFMA resample: out[f,p] = sum_k x[f*441+k-17] * kt[k][p] ----------------
// Split-bf16 (3-pass) GEMM. 2 M-tiles (32 frames) per block, 5 waves x 32 phases.
// A staged in LDS frag-major (wave ds_read = contiguous 1KB, conflict-free);
// B read from global frag-major (wave load = contiguous 1KB, L2-resident 307KB).
#define MT2   32      // 32 blocks per sequence x 32 frames = 1024 >= 1000

__global__ __launch_bounds__(320) void resample_mfma(const float* __restrict__ xlp,
                                                     const unsigned short* __restrict__ kth,
                                                     const unsigned short* __restrict__ ktl,
                                                     float* __restrict__ out) {
    __shared__ unsigned short Ah[2][7680];   // [tile][ks*512 + lane*8 + j]
    __shared__ unsigned short Al[2][7680];   // total 61,440 B -> 2 blocks/CU

    int bid = blockIdx.x;
    int seq = bid / MT2;
    int mt  = bid - seq * MT2;
    int band  = seq / BATCH;
    int batch = seq - band * BATCH;
    int f0 = mt * 32;
    const float* xr = xlp + seq * T_IN;

    // stage 32 frame-windows -> bf16 hi/lo, frag-major
    for (int i = threadIdx.x; i < 32 * 120; i += 320) {
        int r  = i / 120;                 // frame row 0..31
        int q  = i - r * 120;
        int c  = q * 4;                   // tap col base (0..476)
        int fr = f0 + r;
        int base = fr * ORIG_R - WIDTH + c;
        float v0 = (base     >= 0 && base     < T_IN) ? xr[base]     : 0.f;
        float v1 = (base + 1 >= 0 && base + 1 < T_IN) ? xr[base + 1] : 0.f;
        float v2 = (base + 2 >= 0 && base + 2 < T_IN) ? xr[base + 2] : 0.f;
        float v3 = (base + 3 >= 0 && base + 3 < T_IN) ? xr[base + 3] : 0.f;
        unsigned short h0 = f2bf(v0), h1 = f2bf(v1), h2 = f2bf(v2), h3 = f2bf(v3);
        unsigned short l0 = f2bf(v0 - bf2f(h0)), l1 = f2bf(v1 - bf2f(h1));
        unsigned short l2 = f2bf(v2 - bf2f(h2)), l3 = f2bf(v3 - bf2f(h3));
        int tile = r >> 4, m = r & 15;
        int ks = c >> 5, qd = (c >> 3) & 3, j0 = c & 7;   // j0 in {0,4}
        int off = ks * 512 + (qd * 16 + m) * 8 + j0;      // 8B-aligned
        *(short4*)&Ah[tile][off] = make_short4(h0, h1, h2, h3);
        *(short4*)&Al[tile][off] = make_short4(l0, l1, l2, l3);
    }
    __syncthreads();

    int w    = threadIdx.x >> 6;      // 0..4 -> phases p0 = w*32
    int lane = threadIdx.x & 63;
    int l15  = lane & 15;
    int quad = lane >> 4;

    floatx4 acc00 = {0,0,0,0}, acc01 = {0,0,0,0};   // [tile][half]
    floatx4 acc10 = {0,0,0,0}, acc11 = {0,0,0,0};

    const unsigned short* b0h = kth + (w * 2    ) * 7680 + lane * 8;  // pblk = w*2
    const unsigned short* b1h = kth + (w * 2 + 1) * 7680 + lane * 8;  // pblk = w*2+1
    const unsigned short* b0l = ktl + (w * 2    ) * 7680 + lane * 8;
    const unsigned short* b1l = ktl + (w * 2 + 1) * 7680 + lane * 8;
    const unsigned short* a0h = &Ah[0][lane * 8];
    const unsigned short* a1h = &Ah[1][lane * 8];
    const unsigned short* a0l = &Al[0][lane * 8];
    const unsigned short* a1l = &Al[1][lane * 8];

#pragma unroll
    for (int ks = 0; ks < 15; ++ks) {
        int o = ks * 512;
        short8 kh0 = *(const short8*)(b0h + o);
        short8 kh1 = *(const short8*)(b1h + o);
        short8 kl0 = *(const short8*)(b0l + o);
        short8 kl1 = *(const short8*)(b1l + o);
        short8 ah0 = *(const short8*)(a0h + o);
        short8 al0 = *(const short8*)(a0l + o);
        short8 ah1 = *(const short8*)(a1h + o);
        short8 al1 = *(const short8*)(a1l + o);

        acc00 = __builtin_amdgcn_mfma_f32_16x16x32_bf16(ah0, kh0, acc00, 0, 0, 0);
        acc00 = __builtin_amdgcn_mfma_f32_16x16x32_bf16(ah0, kl0, acc00, 0, 0, 0);
        acc00 = __builtin_amdgcn_mfma_f32_16x16x32_bf16(al0, kh0, acc00, 0, 0, 0);
        acc01 = __builtin_amdgcn_mfma_f32_16x16x32_bf16(ah0, kh1, acc01, 0, 0, 0);
        acc01 = __builtin_amdgcn_mfma_f32_16x16x32_bf16(ah0, kl1, acc01, 0, 0, 0);
        acc01 = __builtin_amdgcn_mfma_f32_16x16x32_bf16(al0, kh1, acc01, 0, 0, 0);
        acc10 = __builtin_amdgcn_mfma_f32_16x16x32_bf16(ah1, kh0, acc10, 0, 0, 0);
        acc10 = __builtin_amdgcn_mfma_f32_16x16x32_bf16(ah1, kl0, acc10, 0, 0, 0);
        acc10 = __builtin_amdgcn_mfma_f32_16x16x32_bf16(al1, kh0, acc10, 0, 0, 0);
        acc11 = __builtin_amdgcn_mfma_f32_16x16x32_bf16(ah1, kh1, acc11, 0, 0, 0);
        acc11 = __builtin_amdgcn_mfma_f32_16x16x32_bf16(ah1, kl1, acc11, 0, 0, 0);
        acc11 = __builtin_amdgcn_mfma_f32_16x16x32_bf16(al1, kh1, acc11, 0, 0, 0);
    }

    // C/D layout: n = lane&15 (phase), m = quad*4 + reg (frame) -- verified R7
    int obase = (batch * NB + band) * TB_OUT;
    int p0 = w * 32;
#pragma unroll
    for (int r = 0; r < 4; ++r) {
        int fr0 = f0 + quad * 4 + r;
        int fr1 = fr0 + 16;
        if (fr0 < NFRAMES) {
            out[obase + fr0 * NEW_R + p0 + l15]      = acc00[r];
            out[obase + fr0 * NEW_R + p0 + 16 + l15] = acc01[r];
        }
        if (fr1 < NFRAMES) {
            out[obase + fr1 * NEW_R + p0 + l15]      = acc10[r];
            out[obase + fr1 * NEW_R + p0 + 16 + l15] = acc11[r];
        }
    }
}

// ---------------- host ----------------
extern "C" void kernel_launch(void* const* d_in, const int* in_sizes, int n_in,
                              void* d_out, int out_size, void* d_ws, size_t ws_size,
                              hipStream_t stream) {
    const float*    x   = (const float*)d_in[0];
    float*          out = (float*)d_out;
    unsigned short* kth = (unsigned short*)((char*)d_ws + KTH_OFF);
    unsigned short* ktl = (unsigned short*)((char*)d_ws + KTL_OFF);
    float*          xlp = (float*)((char*)d_ws + XLP_OFF);

    ScanParams P;
    const double centers[NB] = {4000.0, 12000.0, 19025.0};
    const double Qs[NB]      = {0.5, 1.5, 19025.0 / 6050.0};
    for (int b = 0; b < NB; ++b) {
        double c  = centers[b], Q = Qs[b];
        double w0 = 2.0 * M_PI * c / 44100.0;
        double al = sin(w0) / (2.0 * Q);
        double a0 = 1.0 + al;
        P.b0[b] = (float)(al / a0);
        P.a1[b] = (float)(-2.0 * cos(w0) / a0);
        P.a2[b] = (float)((1.0 - al) / a0);
        P.w[b]  = 6.283185307179586f * (float)c;   // fl32(fl32(2pi)*c), validated
    }
    {
        double cut = 0.45 * 16000.0;
        double Q   = 0.7071067811865476;
        double w0  = 2.0 * M_PI * cut / 44100.0;
        double al  = sin(w0) / (2.0 * Q);
        double cs  = cos(w0);
        double a0  = 1.0 + al;
        P.lb0 = (float)(((1.0 - cs) / 2.0) / a0);
        P.lb1 = (float)((1.0 - cs) / a0);
        P.lb2 = P.lb0;
        P.la1 = (float)(-2.0 * cs / a0);
        P.la2 = (float)((1.0 - al) / a0);
    }

    // 1) frag-major bf16-split sinc tables
    kt_init_kernel<<<dim3((NEW_R * KP + 255) / 256), dim3(256), 0, stream>>>(kth, ktl);

    // 2) fused IIR cascade -> xlp (24 x 441000 f32)
    int nthreads = NSEQ * NCHUNK;                    // 63000
    scan_kernel<<<dim3((nthreads + 255) / 256), dim3(256), 0, stream>>>(x, xlp, P);

    // 3) MFMA polyphase resample -> out (8 x 3 x 160000)
    resample_mfma<<<dim3(NSEQ * MT2), dim3(320), 0, stream>>>(xlp, kth, ktl, out);
}